// Round 1
// baseline (1627.795 us; speedup 1.0000x reference)
//
#include <hip/hip_runtime.h>
#include <hip/hip_bf16.h>
#include <stdint.h>

#define N_TOK 4096
#define DIM   2048
#define VOCAB 50257
#define VPAD  50304   // 393 * 128
#define IGNORE_IDX (-100)

typedef short  bf16x8 __attribute__((ext_vector_type(8)));
typedef float  f32x4  __attribute__((ext_vector_type(4)));
typedef unsigned short u16x8 __attribute__((ext_vector_type(8)));

typedef const __attribute__((address_space(1))) unsigned int* gptr_t;
typedef __attribute__((address_space(3))) unsigned int*       lptr_t;

__device__ __forceinline__ unsigned short f2bf(float f) {
  union { float f; uint32_t u; } c; c.f = f;
  uint32_t u = c.u;
  return (unsigned short)((u + 0x7FFFu + ((u >> 16) & 1u)) >> 16);
}

// ---- fp32 -> bf16 conversion, weight padded to VPAD rows (pad = 0) ----
__global__ void cvt_weight(const float* __restrict__ w, unsigned short* __restrict__ o) {
  const int t   = blockIdx.x * 256 + threadIdx.x;
  const int idx = t << 3;                    // 8 elements per thread
  const int v   = idx >> 11;                 // / DIM
  u16x8 r = {0, 0, 0, 0, 0, 0, 0, 0};
  if (v < VOCAB) {
    const float4* p = (const float4*)(w + idx);
    const float4 x0 = p[0];
    const float4 x1 = p[1];
    r[0] = f2bf(x0.x); r[1] = f2bf(x0.y); r[2] = f2bf(x0.z); r[3] = f2bf(x0.w);
    r[4] = f2bf(x1.x); r[5] = f2bf(x1.y); r[6] = f2bf(x1.z); r[7] = f2bf(x1.w);
  }
  *(u16x8*)(o + idx) = r;
}

__global__ void cvt_input(const float* __restrict__ a, unsigned short* __restrict__ o) {
  const int t   = blockIdx.x * 256 + threadIdx.x;
  const int idx = t << 3;
  const float4* p = (const float4*)(a + idx);
  const float4 x0 = p[0];
  const float4 x1 = p[1];
  u16x8 r;
  r[0] = f2bf(x0.x); r[1] = f2bf(x0.y); r[2] = f2bf(x0.z); r[3] = f2bf(x0.w);
  r[4] = f2bf(x1.x); r[5] = f2bf(x1.y); r[6] = f2bf(x1.z); r[7] = f2bf(x1.w);
  *(u16x8*)(o + idx) = r;
}

// ---- fused GEMM + online partial-sumexp + target-logit capture ----
// C[m, v] = sum_k input[m,k] * weight[v,k]   (both K-contiguous -> NT GEMM)
// 128x128 tile, BK=32, 4 waves (2x2), 4x4 frags of 16x16x32 bf16 MFMA per wave.
__global__ __launch_bounds__(256) void flce_gemm(
    const unsigned short* __restrict__ A,   // [N_TOK][DIM]  bf16
    const unsigned short* __restrict__ B,   // [VPAD][DIM]   bf16
    const float* __restrict__ bias,         // [VOCAB]
    const int* __restrict__ target,         // [N_TOK]
    float* __restrict__ sumexp,             // [N_TOK] (pre-zeroed)
    float* __restrict__ tgtlog)             // [N_TOK]
{
  __shared__ unsigned short As[128 * 32];   // 8 KB
  __shared__ unsigned short Bs[128 * 32];   // 8 KB
  __shared__ int tgt_s[128];

  const int tid  = threadIdx.x;
  const int lane = tid & 63;
  const int wave = tid >> 6;
  const int wm   = wave >> 1;               // wave row (0..1) -> 64 rows
  const int wn   = wave & 1;                // wave col (0..1) -> 64 cols
  const int m0   = blockIdx.x * 128;
  const int v0   = blockIdx.y * 128;

  if (tid < 128) tgt_s[tid] = target[m0 + tid];

  // staging: 512 x 16B segments per matrix; thread t covers segs t and t+256.
  // seg s -> row s>>2, k-offset (s&3)*8. LDS dest byte = s*16 (contiguous,
  // matching wave-uniform-base + lane*16 semantics of global_load_lds).
  const int r0 = tid >> 2;
  const int c0 = (tid & 3) * 8;
  const unsigned short* ag0 = A + (m0 + r0)      * DIM + c0;
  const unsigned short* ag1 = A + (m0 + 64 + r0) * DIM + c0;
  const unsigned short* bg0 = B + (v0 + r0)      * DIM + c0;
  const unsigned short* bg1 = B + (v0 + 64 + r0) * DIM + c0;
  unsigned short* al0 = As + tid * 8;
  unsigned short* al1 = As + (tid + 256) * 8;
  unsigned short* bl0 = Bs + tid * 8;
  unsigned short* bl1 = Bs + (tid + 256) * 8;

  f32x4 acc[4][4];
#pragma unroll
  for (int i = 0; i < 4; i++)
#pragma unroll
    for (int j = 0; j < 4; j++) acc[i][j] = (f32x4){0.f, 0.f, 0.f, 0.f};

  const int mrow = lane & 15;               // row/col within 16x16 frag
  const int quad = lane >> 4;               // k-group for A/B, row-group for C

  for (int kt = 0; kt < DIM; kt += 32) {
    __syncthreads();   // previous iteration's ds_reads done before overwrite
    __builtin_amdgcn_global_load_lds((gptr_t)(const void*)(ag0 + kt), (lptr_t)(void*)al0, 16, 0, 0);
    __builtin_amdgcn_global_load_lds((gptr_t)(const void*)(ag1 + kt), (lptr_t)(void*)al1, 16, 0, 0);
    __builtin_amdgcn_global_load_lds((gptr_t)(const void*)(bg0 + kt), (lptr_t)(void*)bl0, 16, 0, 0);
    __builtin_amdgcn_global_load_lds((gptr_t)(const void*)(bg1 + kt), (lptr_t)(void*)bl1, 16, 0, 0);
    __syncthreads();   // drains vmcnt(0): staged data visible

    bf16x8 av[4], bv[4];
#pragma unroll
    for (int f = 0; f < 4; f++)
      av[f] = *(const bf16x8*)(As + (wm * 64 + f * 16 + mrow) * 32 + quad * 8);
#pragma unroll
    for (int f = 0; f < 4; f++)
      bv[f] = *(const bf16x8*)(Bs + (wn * 64 + f * 16 + mrow) * 32 + quad * 8);

#pragma unroll
    for (int i = 0; i < 4; i++)
#pragma unroll
      for (int j = 0; j < 4; j++)
        acc[i][j] = __builtin_amdgcn_mfma_f32_16x16x32_bf16(av[i], bv[j], acc[i][j], 0, 0, 0);
  }

  // ---- epilogue: bias add, exp, per-row partial sums, target logit ----
  // C/D layout (verified m89): col = lane&15, row = (lane>>4)*4 + reg
  const int colb = v0 + wn * 64;
#pragma unroll
  for (int i = 0; i < 4; i++) {
    const int rowl = wm * 64 + i * 16 + quad * 4;   // local row base (reg adds 0..3)
    float rs[4] = {0.f, 0.f, 0.f, 0.f};
#pragma unroll
    for (int j = 0; j < 4; j++) {
      const int colg = colb + j * 16 + mrow;
      if (colg < VOCAB) {
        const float bvv = bias[colg];
#pragma unroll
        for (int r = 0; r < 4; r++) {
          const float lg = acc[i][j][r] + bvv;
          rs[r] += __expf(lg);
          if (tgt_s[rowl + r] == colg) tgtlog[m0 + rowl + r] = lg;
        }
      }
    }
#pragma unroll
    for (int r = 0; r < 4; r++) {
      float v = rs[r];
      v += __shfl_xor(v, 1);
      v += __shfl_xor(v, 2);
      v += __shfl_xor(v, 4);
      v += __shfl_xor(v, 8);
      if (mrow == 0) atomicAdd(&sumexp[m0 + rowl + r], v);
    }
  }
}

// ---- final scalar reduction: loss and z_loss ----
__global__ void flce_final(const float* __restrict__ sumexp,
                           const float* __restrict__ tgtlog,
                           const int* __restrict__ target,
                           float* __restrict__ out) {
  const int tid = threadIdx.x;
  float ls = 0.f, zs = 0.f;
  int cnt = 0;
  for (int r = tid; r < N_TOK; r += 256) {
    const int t = target[r];
    if (t != IGNORE_IDX) {
      const float lse = logf(sumexp[r]);
      const float z = 1e-4f * lse * lse;
      ls += (lse - tgtlog[r]) + z;
      zs += z;
      cnt++;
    }
  }
#pragma unroll
  for (int off = 32; off > 0; off >>= 1) {
    ls += __shfl_down(ls, off);
    zs += __shfl_down(zs, off);
    cnt += __shfl_down(cnt, off);
  }
  __shared__ float sls[4], szs[4];
  __shared__ int scnt[4];
  const int lane = tid & 63, wv = tid >> 6;
  if (lane == 0) { sls[wv] = ls; szs[wv] = zs; scnt[wv] = cnt; }
  __syncthreads();
  if (tid == 0) {
    float L = 0.f, Z = 0.f;
    int C = 0;
    for (int w = 0; w < 4; w++) { L += sls[w]; Z += szs[w]; C += scnt[w]; }
    const float n = (float)(C > 0 ? C : 1);
    out[0] = L / n;
    out[1] = Z / n;
  }
}

extern "C" void kernel_launch(void* const* d_in, const int* in_sizes, int n_in,
                              void* d_out, int out_size, void* d_ws, size_t ws_size,
                              hipStream_t stream) {
  const float* input  = (const float*)d_in[0];
  const float* weight = (const float*)d_in[1];
  const float* bias   = (const float*)d_in[2];
  const int*   target = (const int*)d_in[3];
  float* out = (float*)d_out;

  unsigned short* wbf = (unsigned short*)d_ws;               // VPAD*DIM bf16
  unsigned short* abf = wbf + (size_t)VPAD * DIM;            // N_TOK*DIM bf16
  float* sumexp = (float*)(abf + (size_t)N_TOK * DIM);       // N_TOK f32
  float* tgtlog = sumexp + N_TOK;                            // N_TOK f32

  hipMemsetAsync(sumexp, 0, N_TOK * sizeof(float), stream);
  cvt_weight<<<(VPAD * DIM) / 2048, 256, 0, stream>>>(weight, wbf);
  cvt_input<<<(N_TOK * DIM) / 2048, 256, 0, stream>>>(input, abf);
  flce_gemm<<<dim3(N_TOK / 128, VPAD / 128), 256, 0, stream>>>(abf, wbf, bias, target, sumexp, tgtlog);
  flce_final<<<1, 256, 0, stream>>>(sumexp, tgtlog, target, out);
}